// Round 1
// baseline (336.917 us; speedup 1.0000x reference)
//
#include <hip/hip_runtime.h>
#include <math.h>

#define DIM 64
#define TILE 64

// ---------------- target-score kernel: one wave per row ----------------
__global__ __launch_bounds__(256) void nce_target_kernel(
    const float* __restrict__ inp, const float* __restrict__ embs,
    const int* __restrict__ tgt, const float* __restrict__ lpn,
    float cadd, float* __restrict__ partials)
{
    int tid = threadIdx.x;
    int wave = tid >> 6, lane = tid & 63;
    int r = blockIdx.x * 4 + wave;
    int t = tgt[r];
    float a = inp[(size_t)r * DIM + lane];
    float e = embs[(size_t)t * DIM + lane];
    float p = a * e;
    #pragma unroll
    for (int off = 32; off > 0; off >>= 1) p += __shfl_xor(p, off);
    __shared__ float red[4];
    if (lane == 0) {
        float x0 = p + cadd - lpn[t];
        // BCE with label 1: max(x,0) - x + log1p(exp(-|x|))
        red[wave] = fmaxf(x0, 0.f) - x0 + log1pf(__expf(-fabsf(x0)));
    }
    __syncthreads();
    if (tid == 0) partials[blockIdx.x] = red[0] + red[1] + red[2] + red[3];
}

// ------------- noise GEMM + softplus kernel: 64x64 tile, 4x4 micro -------------
__global__ __launch_bounds__(256) void nce_noise_kernel(
    const float* __restrict__ inp, const float* __restrict__ embs,
    const int* __restrict__ ns, const float* __restrict__ lpn,
    float cadd, int nColTiles, float* __restrict__ partials)
{
    __shared__ float As[DIM][TILE + 4];   // As[d][row], padded: row start 16B-aligned
    __shared__ float Bs[DIM][TILE + 4];   // Bs[d][col]
    __shared__ float cks[TILE];
    __shared__ float red[4];

    int tid = threadIdx.x;
    int rowTile = blockIdx.x / nColTiles;
    int colTile = blockIdx.x % nColTiles;
    int rBase = rowTile * TILE;
    int cBase = colTile * TILE;

    // stage A (input rows) transposed into LDS
    const float4* Ag4 = (const float4*)(inp + (size_t)rBase * DIM);
    #pragma unroll
    for (int c = 0; c < 4; ++c) {
        int f = c * 256 + tid;       // 0..1023 float4s = 64 rows x 16 quads
        int row = f >> 4;
        int dq = f & 15;
        float4 v = Ag4[f];
        As[dq*4+0][row] = v.x; As[dq*4+1][row] = v.y;
        As[dq*4+2][row] = v.z; As[dq*4+3][row] = v.w;
    }
    // stage B (gathered noise embeddings) transposed into LDS
    #pragma unroll
    for (int c = 0; c < 4; ++c) {
        int f = c * 256 + tid;
        int col = f >> 4;
        int dq = f & 15;
        int item = ns[cBase + col];
        float4 v = ((const float4*)(embs + (size_t)item * DIM))[dq];
        Bs[dq*4+0][col] = v.x; Bs[dq*4+1][col] = v.y;
        Bs[dq*4+2][col] = v.z; Bs[dq*4+3][col] = v.w;
    }
    if (tid < TILE) cks[tid] = cadd - lpn[ns[cBase + tid]];
    __syncthreads();

    int tx = tid & 15, ty = tid >> 4;
    float acc[4][4] = {};
    #pragma unroll 16
    for (int d = 0; d < DIM; ++d) {
        float4 a = *(const float4*)&As[d][ty * 4];
        float4 b = *(const float4*)&Bs[d][tx * 4];
        float av[4] = {a.x, a.y, a.z, a.w};
        float bv[4] = {b.x, b.y, b.z, b.w};
        #pragma unroll
        for (int i = 0; i < 4; ++i)
            #pragma unroll
            for (int j = 0; j < 4; ++j)
                acc[i][j] = fmaf(av[i], bv[j], acc[i][j]);
    }

    // softplus epilogue (BCE label 0: max(x,0) + log1p(exp(-|x|)))
    float s = 0.f;
    #pragma unroll
    for (int i = 0; i < 4; ++i)
        #pragma unroll
        for (int j = 0; j < 4; ++j) {
            float x = acc[i][j] + cks[tx * 4 + j];
            s += fmaxf(x, 0.f) + log1pf(__expf(-fabsf(x)));
        }

    // block reduction
    #pragma unroll
    for (int off = 32; off > 0; off >>= 1) s += __shfl_xor(s, off);
    int wave = tid >> 6, lane = tid & 63;
    if (lane == 0) red[wave] = s;
    __syncthreads();
    if (tid == 0) partials[blockIdx.x] = red[0] + red[1] + red[2] + red[3];
}

// ---------------- finalize: sum all partials, divide by B*N ----------------
__global__ __launch_bounds__(256) void nce_finalize_kernel(
    const float* __restrict__ partials, int n, float invRows, float* __restrict__ out)
{
    int tid = threadIdx.x;
    float s = 0.f;
    for (int i = tid; i < n; i += 256) s += partials[i];
    #pragma unroll
    for (int off = 32; off > 0; off >>= 1) s += __shfl_xor(s, off);
    __shared__ float red[4];
    int wave = tid >> 6, lane = tid & 63;
    if (lane == 0) red[wave] = s;
    __syncthreads();
    if (tid == 0) out[0] = (red[0] + red[1] + red[2] + red[3]) * invRows;
}

extern "C" void kernel_launch(void* const* d_in, const int* in_sizes, int n_in,
                              void* d_out, int out_size, void* d_ws, size_t ws_size,
                              hipStream_t stream) {
    const int*   target = (const int*)d_in[0];
    const float* input  = (const float*)d_in[1];
    const float* embs   = (const float*)d_in[2];
    const int*   ns     = (const int*)d_in[3];
    const float* lpn    = (const float*)d_in[4];
    float* out = (float*)d_out;

    int nRows = in_sizes[0];            // B*N = 6400
    int K     = in_sizes[3];            // 1024
    long long V = in_sizes[4];          // 1,000,000
    float NORM = logf((float)V);
    float LOGK = logf((float)K);
    float cadd = -(NORM + LOGK);        // x = score + cadd - lpn[idx]

    float* ws = (float*)d_ws;
    int nRowTiles = nRows / TILE;       // 100
    int nColTiles = K / TILE;           // 16
    int nMain = nRowTiles * nColTiles;  // 1600
    int nTgtBlocks = nRows / 4;         // 1600
    float* pMain = ws;                  // [nMain]
    float* pTgt  = ws + nMain;          // [nTgtBlocks], contiguous after pMain

    nce_target_kernel<<<nTgtBlocks, 256, 0, stream>>>(input, embs, target, lpn, cadd, pTgt);
    nce_noise_kernel<<<nMain, 256, 0, stream>>>(input, embs, ns, lpn, cadd, nColTiles, pMain);
    nce_finalize_kernel<<<1, 256, 0, stream>>>(ws, nMain + nTgtBlocks,
                                               1.0f / (float)nRows, out);
}

// Round 4
// 316.179 us; speedup vs baseline: 1.0656x; 1.0656x over previous
//
#include <hip/hip_runtime.h>
#include <math.h>

#define DIM 64
#define TILE 64

__device__ __forceinline__ float softplus_fast(float z) {
    // softplus(z) = max(z,0) + log(1+exp(-|z|)); hardware exp/log, ~1e-6 rel err
    return fmaxf(z, 0.f) + __logf(1.f + __expf(-fabsf(z)));
}

// ---- fused main kernel: noise GEMM tile + softplus + (colTile==0) target terms ----
__global__ __launch_bounds__(256) void nce_main_kernel(
    const float* __restrict__ inp, const float* __restrict__ embs,
    const int* __restrict__ tgt, const int* __restrict__ ns,
    const float* __restrict__ lpn, float cadd, int nColTiles,
    float* __restrict__ partials)
{
    __shared__ float As[DIM][TILE + 4];   // As[d][row], row start 16B-aligned (68*4=272B)
    __shared__ float Bs[DIM][TILE + 4];   // Bs[d][col]
    __shared__ float cks[TILE];
    __shared__ float red[4];

    int tid = threadIdx.x;
    int rowTile = blockIdx.x / nColTiles;
    int colTile = blockIdx.x % nColTiles;
    int rBase = rowTile * TILE;
    int cBase = colTile * TILE;

    float s = 0.f;

    // ---- target terms: only colTile==0 blocks, 4 threads per row ----
    if (colTile == 0) {
        int r4 = tid >> 2, q = tid & 3;
        int row = rBase + r4;
        int t = tgt[row];
        const float4* er = (const float4*)(embs + (size_t)t * DIM) + q * 4;
        const float4* ir = (const float4*)(inp + (size_t)row * DIM) + q * 4;
        float p = 0.f;
        #pragma unroll
        for (int j = 0; j < 4; ++j) {
            float4 e = er[j]; float4 a = ir[j];
            p += a.x * e.x + a.y * e.y + a.z * e.z + a.w * e.w;
        }
        p += __shfl_xor(p, 1);
        p += __shfl_xor(p, 2);
        if (q == 0) {
            float x0 = p + cadd - lpn[t];
            s += softplus_fast(-x0);   // BCE label 1 == softplus(-x0)
        }
    }

    // ---- stage A (input rows) transposed into LDS ----
    const float4* Ag4 = (const float4*)(inp + (size_t)rBase * DIM);
    #pragma unroll
    for (int c = 0; c < 4; ++c) {
        int f = c * 256 + tid;       // 1024 float4s = 64 rows x 16 quads
        int row = f >> 4;
        int dq = f & 15;
        float4 v = Ag4[f];
        As[dq*4+0][row] = v.x; As[dq*4+1][row] = v.y;
        As[dq*4+2][row] = v.z; As[dq*4+3][row] = v.w;
    }
    // ---- stage B (gathered noise embeddings) transposed into LDS ----
    #pragma unroll
    for (int c = 0; c < 4; ++c) {
        int f = c * 256 + tid;
        int col = f >> 4;
        int dq = f & 15;
        int item = ns[cBase + col];
        float4 v = ((const float4*)(embs + (size_t)item * DIM))[dq];
        Bs[dq*4+0][col] = v.x; Bs[dq*4+1][col] = v.y;
        Bs[dq*4+2][col] = v.z; Bs[dq*4+3][col] = v.w;
    }
    if (tid < TILE) cks[tid] = cadd - lpn[ns[cBase + tid]];
    __syncthreads();

    // ---- 4x4 micro-tile fp32 GEMM ----
    int tx = tid & 15, ty = tid >> 4;
    float acc[4][4] = {};
    #pragma unroll 16
    for (int d = 0; d < DIM; ++d) {
        float4 a = *(const float4*)&As[d][ty * 4];
        float4 b = *(const float4*)&Bs[d][tx * 4];
        float av[4] = {a.x, a.y, a.z, a.w};
        float bv[4] = {b.x, b.y, b.z, b.w};
        #pragma unroll
        for (int i = 0; i < 4; ++i)
            #pragma unroll
            for (int j = 0; j < 4; ++j)
                acc[i][j] = fmaf(av[i], bv[j], acc[i][j]);
    }

    // ---- softplus epilogue (BCE label 0) ----
    #pragma unroll
    for (int i = 0; i < 4; ++i)
        #pragma unroll
        for (int j = 0; j < 4; ++j)
            s += softplus_fast(acc[i][j] + cks[tx * 4 + j]);

    // ---- block reduction ----
    #pragma unroll
    for (int off = 32; off > 0; off >>= 1) s += __shfl_xor(s, off);
    int wave = tid >> 6, lane = tid & 63;
    if (lane == 0) red[wave] = s;
    __syncthreads();
    if (tid == 0) partials[blockIdx.x] = red[0] + red[1] + red[2] + red[3];
}

// ---------------- finalize: sum all partials, divide by B*N ----------------
__global__ __launch_bounds__(256) void nce_finalize_kernel(
    const float* __restrict__ partials, int n, float invRows, float* __restrict__ out)
{
    int tid = threadIdx.x;
    float s = 0.f;
    for (int i = tid; i < n; i += 256) s += partials[i];
    #pragma unroll
    for (int off = 32; off > 0; off >>= 1) s += __shfl_xor(s, off);
    __shared__ float red[4];
    int wave = tid >> 6, lane = tid & 63;
    if (lane == 0) red[wave] = s;
    __syncthreads();
    if (tid == 0) out[0] = (red[0] + red[1] + red[2] + red[3]) * invRows;
}

extern "C" void kernel_launch(void* const* d_in, const int* in_sizes, int n_in,
                              void* d_out, int out_size, void* d_ws, size_t ws_size,
                              hipStream_t stream) {
    const int*   target = (const int*)d_in[0];
    const float* input  = (const float*)d_in[1];
    const float* embs   = (const float*)d_in[2];
    const int*   ns     = (const int*)d_in[3];
    const float* lpn    = (const float*)d_in[4];
    float* out = (float*)d_out;

    int nRows = in_sizes[0];            // B*N = 6400
    int K     = in_sizes[3];            // 1024
    long long V = in_sizes[4];          // 1,000,000
    float NORM = logf((float)V);
    float LOGK = logf((float)K);
    float cadd = -(NORM + LOGK);        // x = score + cadd - lpn[idx]

    float* ws = (float*)d_ws;
    int nRowTiles = nRows / TILE;       // 100
    int nColTiles = K / TILE;           // 16
    int nMain = nRowTiles * nColTiles;  // 1600

    nce_main_kernel<<<nMain, 256, 0, stream>>>(input, embs, target, ns, lpn,
                                               cadd, nColTiles, ws);
    nce_finalize_kernel<<<1, 256, 0, stream>>>(ws, nMain, 1.0f / (float)nRows, out);
}

// Round 5
// 299.253 us; speedup vs baseline: 1.1259x; 1.0566x over previous
//
#include <hip/hip_runtime.h>
#include <math.h>

#define DIM 64
#define TILE 64
#define LDK 72   // padded k-stride in bf16 units (144 B = 16B-aligned, 2-way-max banks)

typedef __attribute__((ext_vector_type(8))) short short8v;   // 8 bf16 = 4 VGPR
typedef __attribute__((ext_vector_type(4))) float floatx4;   // MFMA acc

struct ushort4s { unsigned short x, y, z, w; };

__device__ __forceinline__ float softplus_fast(float z) {
    // softplus(z) = max(z,0) + log(1+exp(-|z|)); hardware exp/log
    return fmaxf(z, 0.f) + __logf(1.f + __expf(-fabsf(z)));
}

__device__ __forceinline__ unsigned short f2bf(float x) {
    // fp32 -> bf16 round-to-nearest-even
    unsigned u = __builtin_bit_cast(unsigned, x);
    return (unsigned short)((u + 0x7fffu + ((u >> 16) & 1u)) >> 16);
}

// ---- fused main kernel: bf16 MFMA noise-GEMM tile + softplus + 4 target rows ----
__global__ __launch_bounds__(256, 6) void nce_main_kernel(
    const float* __restrict__ inp, const float* __restrict__ embs,
    const int* __restrict__ tgt, const int* __restrict__ ns,
    const float* __restrict__ lpn, float cadd, int nColTiles,
    float* __restrict__ partials)
{
    __shared__ unsigned short A_lds[TILE * LDK];  // A[row][k] bf16
    __shared__ unsigned short B_lds[TILE * LDK];  // B[col][k] bf16
    __shared__ float cks[TILE];
    __shared__ float red[4];

    int tid = threadIdx.x;
    int wave = tid >> 6, lane = tid & 63;
    int rowTile = blockIdx.x / nColTiles;
    int colTile = blockIdx.x % nColTiles;
    int rBase = rowTile * TILE;
    int cBase = colTile * TILE;

    float s = 0.f;

    // ---- target terms: 4 rows per block (this block's slice), wave 0 only ----
    if (wave == 0) {
        int row = rBase + colTile * 4 + (lane >> 4);
        int t = tgt[row];
        float4 e = ((const float4*)(embs + (size_t)t * DIM))[lane & 15];
        float4 a = ((const float4*)(inp + (size_t)row * DIM))[lane & 15];
        float p = a.x * e.x + a.y * e.y + a.z * e.z + a.w * e.w;
        p += __shfl_xor(p, 1);
        p += __shfl_xor(p, 2);
        p += __shfl_xor(p, 4);
        p += __shfl_xor(p, 8);
        if ((lane & 15) == 0) {
            float x0 = p + cadd - lpn[t];
            s += softplus_fast(-x0);   // BCE label 1 == softplus(-x0)
        }
    }

    // ---- stage A (input rows) as bf16 into LDS ----
    const float4* Ag4 = (const float4*)(inp + (size_t)rBase * DIM);
    #pragma unroll
    for (int c = 0; c < 4; ++c) {
        int f = c * 256 + tid;          // 1024 float4s = 64 rows x 16 quads
        int row = f >> 4;
        int kq = f & 15;
        float4 v = Ag4[f];
        ushort4s b = { f2bf(v.x), f2bf(v.y), f2bf(v.z), f2bf(v.w) };
        *(ushort4s*)&A_lds[row * LDK + kq * 4] = b;
    }
    // ---- stage B (gathered noise embeddings) as bf16 into LDS ----
    #pragma unroll
    for (int c = 0; c < 4; ++c) {
        int f = c * 256 + tid;
        int col = f >> 4;
        int kq = f & 15;
        int item = ns[cBase + col];
        float4 v = ((const float4*)(embs + (size_t)item * DIM))[kq];
        ushort4s b = { f2bf(v.x), f2bf(v.y), f2bf(v.z), f2bf(v.w) };
        *(ushort4s*)&B_lds[col * LDK + kq * 4] = b;
    }
    if (tid < TILE) cks[tid] = cadd - lpn[ns[cBase + tid]];
    __syncthreads();

    // ---- MFMA: each wave computes 16 rows x 64 cols ----
    // A-frag: lane holds A[wrow + (lane&15)][(lane>>4)*8 + 0..7]
    int ar = wave * 16 + (lane & 15);
    int ak = (lane >> 4) * 8;
    short8v a0 = *(const short8v*)&A_lds[ar * LDK + ak];        // k = 0..31
    short8v a1 = *(const short8v*)&A_lds[ar * LDK + 32 + ak];   // k = 32..63

    #pragma unroll
    for (int cf = 0; cf < 4; ++cf) {
        int bc = cf * 16 + (lane & 15);
        short8v b0 = *(const short8v*)&B_lds[bc * LDK + ak];
        short8v b1 = *(const short8v*)&B_lds[bc * LDK + 32 + ak];
        floatx4 acc = {0.f, 0.f, 0.f, 0.f};
        acc = __builtin_amdgcn_mfma_f32_16x16x32_bf16(a0, b0, acc, 0, 0, 0);
        acc = __builtin_amdgcn_mfma_f32_16x16x32_bf16(a1, b1, acc, 0, 0, 0);
        float ck = cks[cf * 16 + (lane & 15)];   // C-layout: col = lane&15
        #pragma unroll
        for (int j = 0; j < 4; ++j)
            s += softplus_fast(acc[j] + ck);     // BCE label 0 == softplus(x)
    }

    // ---- block reduction ----
    #pragma unroll
    for (int off = 32; off > 0; off >>= 1) s += __shfl_xor(s, off);
    if (lane == 0) red[wave] = s;
    __syncthreads();
    if (tid == 0) partials[blockIdx.x] = red[0] + red[1] + red[2] + red[3];
}

// ---------------- finalize: sum all partials, divide by B*N ----------------
__global__ __launch_bounds__(256) void nce_finalize_kernel(
    const float* __restrict__ partials, int n, float invRows, float* __restrict__ out)
{
    int tid = threadIdx.x;
    float s = 0.f;
    for (int i = tid; i < n; i += 256) s += partials[i];
    #pragma unroll
    for (int off = 32; off > 0; off >>= 1) s += __shfl_xor(s, off);
    __shared__ float red[4];
    int wave = tid >> 6, lane = tid & 63;
    if (lane == 0) red[wave] = s;
    __syncthreads();
    if (tid == 0) out[0] = (red[0] + red[1] + red[2] + red[3]) * invRows;
}

extern "C" void kernel_launch(void* const* d_in, const int* in_sizes, int n_in,
                              void* d_out, int out_size, void* d_ws, size_t ws_size,
                              hipStream_t stream) {
    const int*   target = (const int*)d_in[0];
    const float* input  = (const float*)d_in[1];
    const float* embs   = (const float*)d_in[2];
    const int*   ns     = (const int*)d_in[3];
    const float* lpn    = (const float*)d_in[4];
    float* out = (float*)d_out;

    int nRows = in_sizes[0];            // B*N = 6400
    int K     = in_sizes[3];            // 1024
    long long V = in_sizes[4];          // 1,000,000
    float NORM = logf((float)V);
    float LOGK = logf((float)K);
    float cadd = -(NORM + LOGK);        // x = score + cadd - lpn[idx]

    float* ws = (float*)d_ws;
    int nRowTiles = nRows / TILE;       // 100
    int nColTiles = K / TILE;           // 16
    int nMain = nRowTiles * nColTiles;  // 1600

    nce_main_kernel<<<nMain, 256, 0, stream>>>(input, embs, target, ns, lpn,
                                               cadd, nColTiles, ws);
    nce_finalize_kernel<<<1, 256, 0, stream>>>(ws, nMain, 1.0f / (float)nRows, out);
}